// Round 2
// baseline (2101.127 us; speedup 1.0000x reference)
//
#include <hip/hip_runtime.h>
#include <hip/hip_bf16.h>
#include <math.h>

#define B 4
#define S 2048
#define E 1024
#define A 128

// ---------------------------------------------------------------------------
// Projection: for each (b,s) row, compute q/k/v[a] = dot(x[b,s,:], W[a,:])
// One block per row, 128 threads (thread a owns output dim a).
// X row staged in LDS; W rows read from global (hot in L2 after first pass).
// ---------------------------------------------------------------------------
__global__ __launch_bounds__(128) void proj_kernel(
    const float* __restrict__ X,
    const float* __restrict__ Wk,
    const float* __restrict__ Wq,
    const float* __restrict__ Wv,
    float* __restrict__ Q,
    float* __restrict__ K,
    float* __restrict__ V) {
  __shared__ float xs[E];
  const int row = blockIdx.x;            // b*S + s
  const float* x = X + (size_t)row * E;
  // coalesced float4 staging of the X row
  {
    const float4* x4 = (const float4*)x;
    float4* xs4 = (float4*)xs;
    for (int i = threadIdx.x; i < E / 4; i += blockDim.x) xs4[i] = x4[i];
  }
  __syncthreads();

  const int a = threadIdx.x;             // output dim
  const float4* wk4 = (const float4*)(Wk + (size_t)a * E);
  const float4* wq4 = (const float4*)(Wq + (size_t)a * E);
  const float4* wv4 = (const float4*)(Wv + (size_t)a * E);
  const float4* xs4 = (const float4*)xs;
  float sk = 0.f, sq = 0.f, sv = 0.f;
#pragma unroll 4
  for (int e = 0; e < E / 4; ++e) {
    const float4 xe = xs4[e];            // LDS broadcast (all lanes same addr)
    const float4 k4 = wk4[e];
    const float4 q4 = wq4[e];
    const float4 v4 = wv4[e];
    sk = fmaf(k4.x, xe.x, sk); sk = fmaf(k4.y, xe.y, sk);
    sk = fmaf(k4.z, xe.z, sk); sk = fmaf(k4.w, xe.w, sk);
    sq = fmaf(q4.x, xe.x, sq); sq = fmaf(q4.y, xe.y, sq);
    sq = fmaf(q4.z, xe.z, sq); sq = fmaf(q4.w, xe.w, sq);
    sv = fmaf(v4.x, xe.x, sv); sv = fmaf(v4.y, xe.y, sv);
    sv = fmaf(v4.z, xe.z, sv); sv = fmaf(v4.w, xe.w, sv);
  }
  const size_t o = (size_t)row * A + a;
  Q[o] = sq;
  K[o] = sk;
  V[o] = sv;
}

// ---------------------------------------------------------------------------
// Flash-style causal attention, one block (128 threads) per query row.
// Thread t: computes score for key (j0 + t) within each 128-key tile, and
// owns output dimension t for the PV accumulation. Online softmax.
// ---------------------------------------------------------------------------
__global__ __launch_bounds__(128) void attn_kernel(
    const float* __restrict__ Q,
    const float* __restrict__ K,
    const float* __restrict__ V,
    float* __restrict__ Out) {
  __shared__ float qs[A];    // scaled query
  __shared__ float ps[A];    // tile scores, then tile probabilities

  const int row = blockIdx.x;        // b*S + qi
  const int b = row / S;
  const int qi = row % S;
  const int t = threadIdx.x;

  const float scale = 0.08838834764831845f;  // 1/sqrt(128)
  qs[t] = Q[(size_t)row * A + t] * scale;
  __syncthreads();

  float m = -INFINITY;   // running max
  float l = 0.f;         // running denom
  float o = 0.f;         // running output for dim t

  const int nk = qi + 1;                       // causal: keys 0..qi
  const float* Kb = K + (size_t)b * S * A;
  const float* Vb = V + (size_t)b * S * A;
  const float4* qs4 = (const float4*)qs;

  for (int j0 = 0; j0 < nk; j0 += A) {
    const int j = j0 + t;
    float s = -INFINITY;
    if (j < nk) {
      const float4* kj4 = (const float4*)(Kb + (size_t)j * A);
      float acc = 0.f;
#pragma unroll 8
      for (int e = 0; e < A / 4; ++e) {
        const float4 qe = qs4[e];
        const float4 ke = kj4[e];
        acc = fmaf(qe.x, ke.x, acc); acc = fmaf(qe.y, ke.y, acc);
        acc = fmaf(qe.z, ke.z, acc); acc = fmaf(qe.w, ke.w, acc);
      }
      s = acc;
    }
    __syncthreads();            // protect ps from previous iteration's reads
    ps[t] = s;
    __syncthreads();

    // tile max (broadcast reads from LDS; every thread computes the same)
    float tmax = -INFINITY;
#pragma unroll 8
    for (int jj = 0; jj < A; ++jj) tmax = fmaxf(tmax, ps[jj]);

    const float newm = fmaxf(m, tmax);
    const float alpha = __expf(m - newm);   // first tile: exp(-inf)=0; l=o=0 anyway
    const float p = (s == -INFINITY) ? 0.f : __expf(s - newm);
    m = newm;                               // <-- the round-0 bug: commit running max
    __syncthreads();
    ps[t] = p;
    __syncthreads();

    float tsum = 0.f;
#pragma unroll 8
    for (int jj = 0; jj < A; ++jj) tsum += ps[jj];

    l = l * alpha + tsum;
    o = o * alpha;
    const float* vrow = Vb + (size_t)j0 * A + t;
    // S % A == 0, so every tile's V rows are in-bounds; masked keys have p=0.
#pragma unroll 8
    for (int jj = 0; jj < A; ++jj) {
      o = fmaf(ps[jj], vrow[(size_t)jj * A], o);
    }
  }

  Out[(size_t)row * A + t] = o / l;
}

extern "C" void kernel_launch(void* const* d_in, const int* in_sizes, int n_in,
                              void* d_out, int out_size, void* d_ws, size_t ws_size,
                              hipStream_t stream) {
  const float* X  = (const float*)d_in[0];  // embedded [B,S,E]
  const float* Wk = (const float*)d_in[1];  // [A,E]
  const float* Wq = (const float*)d_in[2];
  const float* Wv = (const float*)d_in[3];
  float* Out = (float*)d_out;               // [B,S,A]

  const size_t qkv_elems = (size_t)B * S * A;     // 1M elems = 4MB each
  float* Q = (float*)d_ws;
  float* K = Q + qkv_elems;
  float* V = K + qkv_elems;

  proj_kernel<<<B * S, 128, 0, stream>>>(X, Wk, Wq, Wv, Q, K, V);
  attn_kernel<<<B * S, 128, 0, stream>>>(Q, K, V, Out);
}

// Round 3
// 790.742 us; speedup vs baseline: 2.6572x; 2.6572x over previous
//
#include <hip/hip_runtime.h>
#include <hip/hip_bf16.h>
#include <math.h>

#define B 4
#define S 2048
#define E 1024
#define A 128

typedef __attribute__((ext_vector_type(8))) short short8;   // 8 bf16 (4 VGPRs)
typedef __attribute__((ext_vector_type(4))) float floatx4;  // MFMA C/D

// fp32 -> bf16 (round-to-nearest-even), bit pattern as short
static __device__ __forceinline__ short f2bf(float f) {
  union { float f; unsigned u; } c;
  c.f = f;
  unsigned r = (c.u + 0x7fffu + ((c.u >> 16) & 1u)) >> 16;
  return (short)r;
}

// ---------------------------------------------------------------------------
// Projection as MFMA bf16 GEMM: C[M=8192, A=128] = X[M,E] . W[A,E]^T
// Grid: (M/128, 3) — blockIdx.y selects Wq/Wk/Wv. 256 threads = 4 waves in a
// 2x2 wave grid; each wave computes a 64x64 sub-tile as 4x4 MFMAs of
// 16x16x32 bf16. LDS tiles As[128][32], Bs[128][32] (bf16), staged through
// registers with on-the-fly fp32->bf16 conversion.
// Fragment layouts (m89/m91-verified): A[m=lane&15][k=quad*8+j];
// C/D: col=lane&15, row=quad*4+reg.
// ---------------------------------------------------------------------------
__global__ __launch_bounds__(256) void proj_gemm(
    const float* __restrict__ X,
    const float* __restrict__ Wq,
    const float* __restrict__ Wk,
    const float* __restrict__ Wv,
    float* __restrict__ Q,
    float* __restrict__ K,
    float* __restrict__ V) {
  __shared__ short As[128 * 32];
  __shared__ short Bs[128 * 32];

  const int m0 = blockIdx.x * 128;
  const int which = blockIdx.y;
  const float* Wp = (which == 0) ? Wq : (which == 1) ? Wk : Wv;
  float* Out = (which == 0) ? Q : (which == 1) ? K : V;

  const int tid = threadIdx.x;
  const int wave = tid >> 6;
  const int lane = tid & 63;
  const int wm = wave & 1;       // wave row in 2x2 grid
  const int wn = wave >> 1;      // wave col
  const int l16 = lane & 15;
  const int quad = lane >> 4;

  floatx4 acc[4][4] = {};        // 64 VGPRs of accumulator

  for (int k0 = 0; k0 < E; k0 += 32) {
    // ---- stage A-tile: X[m0+row][k0 + 4*c4 ..] -> As[row][.] as bf16 ----
#pragma unroll
    for (int i = 0; i < 4; ++i) {
      const int f = tid + i * 256;          // [0,1024) float4 slots
      const int row = f >> 3, c4 = f & 7;
      const float4 xv = *(const float4*)&X[(size_t)(m0 + row) * E + k0 + c4 * 4];
      short4 p;
      p.x = f2bf(xv.x); p.y = f2bf(xv.y); p.z = f2bf(xv.z); p.w = f2bf(xv.w);
      *(short4*)&As[row * 32 + c4 * 4] = p;
    }
    // ---- stage B-tile: W[n][k0 + ...] (W is [A][E] row-major = B^T form) ----
#pragma unroll
    for (int i = 0; i < 4; ++i) {
      const int f = tid + i * 256;
      const int row = f >> 3, c4 = f & 7;
      const float4 wv = *(const float4*)&Wp[(size_t)row * E + k0 + c4 * 4];
      short4 p;
      p.x = f2bf(wv.x); p.y = f2bf(wv.y); p.z = f2bf(wv.z); p.w = f2bf(wv.w);
      *(short4*)&Bs[row * 32 + c4 * 4] = p;
    }
    __syncthreads();

    short8 afr[4], bfr[4];
#pragma unroll
    for (int t = 0; t < 4; ++t)
      afr[t] = *(const short8*)&As[(wm * 64 + t * 16 + l16) * 32 + quad * 8];
#pragma unroll
    for (int t = 0; t < 4; ++t)
      bfr[t] = *(const short8*)&Bs[(wn * 64 + t * 16 + l16) * 32 + quad * 8];

#pragma unroll
    for (int mt = 0; mt < 4; ++mt)
#pragma unroll
      for (int nt = 0; nt < 4; ++nt)
        acc[mt][nt] = __builtin_amdgcn_mfma_f32_16x16x32_bf16(
            afr[mt], bfr[nt], acc[mt][nt], 0, 0, 0);
    __syncthreads();
  }

  // epilogue: C/D layout col=l16 (n), row=quad*4+r (m)
#pragma unroll
  for (int mt = 0; mt < 4; ++mt) {
#pragma unroll
    for (int nt = 0; nt < 4; ++nt) {
      const int n = wn * 64 + nt * 16 + l16;
#pragma unroll
      for (int r = 0; r < 4; ++r) {
        const int m = m0 + wm * 64 + mt * 16 + quad * 4 + r;
        Out[(size_t)m * A + n] = acc[mt][nt][r];
      }
    }
  }
}

// ---------------------------------------------------------------------------
// Flash-style causal attention, one block (128 threads) per query row.
// (unchanged from round 1 — gets the MFMA treatment next round)
// ---------------------------------------------------------------------------
__global__ __launch_bounds__(128) void attn_kernel(
    const float* __restrict__ Q,
    const float* __restrict__ K,
    const float* __restrict__ V,
    float* __restrict__ Out) {
  __shared__ float qs[A];
  __shared__ float ps[A];

  const int row = blockIdx.x;        // b*S + qi
  const int b = row / S;
  const int qi = row % S;
  const int t = threadIdx.x;

  const float scale = 0.08838834764831845f;  // 1/sqrt(128)
  qs[t] = Q[(size_t)row * A + t] * scale;
  __syncthreads();

  float m = -INFINITY;
  float l = 0.f;
  float o = 0.f;

  const int nk = qi + 1;
  const float* Kb = K + (size_t)b * S * A;
  const float* Vb = V + (size_t)b * S * A;
  const float4* qs4 = (const float4*)qs;

  for (int j0 = 0; j0 < nk; j0 += A) {
    const int j = j0 + t;
    float s = -INFINITY;
    if (j < nk) {
      const float4* kj4 = (const float4*)(Kb + (size_t)j * A);
      float acc = 0.f;
#pragma unroll 8
      for (int e = 0; e < A / 4; ++e) {
        const float4 qe = qs4[e];
        const float4 ke = kj4[e];
        acc = fmaf(qe.x, ke.x, acc); acc = fmaf(qe.y, ke.y, acc);
        acc = fmaf(qe.z, ke.z, acc); acc = fmaf(qe.w, ke.w, acc);
      }
      s = acc;
    }
    __syncthreads();
    ps[t] = s;
    __syncthreads();

    float tmax = -INFINITY;
#pragma unroll 8
    for (int jj = 0; jj < A; ++jj) tmax = fmaxf(tmax, ps[jj]);

    const float newm = fmaxf(m, tmax);
    const float alpha = __expf(m - newm);
    const float p = (s == -INFINITY) ? 0.f : __expf(s - newm);
    m = newm;
    __syncthreads();
    ps[t] = p;
    __syncthreads();

    float tsum = 0.f;
#pragma unroll 8
    for (int jj = 0; jj < A; ++jj) tsum += ps[jj];

    l = l * alpha + tsum;
    o = o * alpha;
    const float* vrow = Vb + (size_t)j0 * A + t;
#pragma unroll 8
    for (int jj = 0; jj < A; ++jj) {
      o = fmaf(ps[jj], vrow[(size_t)jj * A], o);
    }
  }

  Out[(size_t)row * A + t] = o / l;
}

extern "C" void kernel_launch(void* const* d_in, const int* in_sizes, int n_in,
                              void* d_out, int out_size, void* d_ws, size_t ws_size,
                              hipStream_t stream) {
  const float* X  = (const float*)d_in[0];  // embedded [B,S,E]
  const float* Wk = (const float*)d_in[1];  // [A,E]
  const float* Wq = (const float*)d_in[2];
  const float* Wv = (const float*)d_in[3];
  float* Out = (float*)d_out;               // [B,S,A]

  const size_t qkv_elems = (size_t)B * S * A;     // 1M elems = 4MB each
  float* Q = (float*)d_ws;
  float* K = Q + qkv_elems;
  float* V = K + qkv_elems;

  dim3 pgrid(B * S / 128, 3);
  proj_gemm<<<pgrid, 256, 0, stream>>>(X, Wq, Wk, Wv, Q, K, V);
  attn_kernel<<<B * S, 128, 0, stream>>>(Q, K, V, Out);
}

// Round 4
// 169.676 us; speedup vs baseline: 12.3832x; 4.6603x over previous
//
#include <hip/hip_runtime.h>
#include <hip/hip_bf16.h>
#include <math.h>

#define B 4
#define S 2048
#define E 1024
#define A 128

typedef __attribute__((ext_vector_type(8))) short short8;   // 8 bf16 (4 VGPRs)
typedef __attribute__((ext_vector_type(4))) float floatx4;  // MFMA C/D

// fp32 -> bf16 (round-to-nearest-even), bit pattern as short
static __device__ __forceinline__ short f2bf(float f) {
  union { float f; unsigned u; } c;
  c.f = f;
  unsigned r = (c.u + 0x7fffu + ((c.u >> 16) & 1u)) >> 16;
  return (short)r;
}

// ---------------------------------------------------------------------------
// Projection as MFMA bf16 GEMM: C[M=8192, A=128] = X[M,E] . W[A,E]^T
// Grid: (M/128, 3) — blockIdx.y selects Wq/Wk/Wv. Outputs are bf16:
//   which==0: Qbf[m][a] = (X.Wq^T)*scale   (scale folded before rounding)
//   which==1: Kbf[m][a]
//   which==2: Vt[b][a][s]  (transposed, so attn PV B-operand reads are rows)
// ---------------------------------------------------------------------------
__global__ __launch_bounds__(256) void proj_gemm(
    const float* __restrict__ X,
    const float* __restrict__ Wq,
    const float* __restrict__ Wk,
    const float* __restrict__ Wv,
    short* __restrict__ Qbf,
    short* __restrict__ Kbf,
    short* __restrict__ Vt) {
  __shared__ short As[128 * 32];
  __shared__ short Bs[128 * 32];

  const int m0 = blockIdx.x * 128;
  const int which = blockIdx.y;
  const float* Wp = (which == 0) ? Wq : (which == 1) ? Wk : Wv;

  const int tid = threadIdx.x;
  const int wave = tid >> 6;
  const int lane = tid & 63;
  const int wm = wave & 1;
  const int wn = wave >> 1;
  const int l16 = lane & 15;
  const int quad = lane >> 4;

  floatx4 acc[4][4] = {};

  for (int k0 = 0; k0 < E; k0 += 32) {
#pragma unroll
    for (int i = 0; i < 4; ++i) {
      const int f = tid + i * 256;
      const int row = f >> 3, c4 = f & 7;
      const float4 xv = *(const float4*)&X[(size_t)(m0 + row) * E + k0 + c4 * 4];
      short4 p;
      p.x = f2bf(xv.x); p.y = f2bf(xv.y); p.z = f2bf(xv.z); p.w = f2bf(xv.w);
      *(short4*)&As[row * 32 + c4 * 4] = p;
    }
#pragma unroll
    for (int i = 0; i < 4; ++i) {
      const int f = tid + i * 256;
      const int row = f >> 3, c4 = f & 7;
      const float4 wv = *(const float4*)&Wp[(size_t)row * E + k0 + c4 * 4];
      short4 p;
      p.x = f2bf(wv.x); p.y = f2bf(wv.y); p.z = f2bf(wv.z); p.w = f2bf(wv.w);
      *(short4*)&Bs[row * 32 + c4 * 4] = p;
    }
    __syncthreads();

    short8 afr[4], bfr[4];
#pragma unroll
    for (int t = 0; t < 4; ++t)
      afr[t] = *(const short8*)&As[(wm * 64 + t * 16 + l16) * 32 + quad * 8];
#pragma unroll
    for (int t = 0; t < 4; ++t)
      bfr[t] = *(const short8*)&Bs[(wn * 64 + t * 16 + l16) * 32 + quad * 8];

#pragma unroll
    for (int mt = 0; mt < 4; ++mt)
#pragma unroll
      for (int nt = 0; nt < 4; ++nt)
        acc[mt][nt] = __builtin_amdgcn_mfma_f32_16x16x32_bf16(
            afr[mt], bfr[nt], acc[mt][nt], 0, 0, 0);
    __syncthreads();
  }

  const float qscale = 0.08838834764831845f;  // 1/sqrt(128)
#pragma unroll
  for (int mt = 0; mt < 4; ++mt) {
#pragma unroll
    for (int nt = 0; nt < 4; ++nt) {
      const int n = wn * 64 + nt * 16 + l16;
      const int mbase = m0 + wm * 64 + mt * 16 + quad * 4;   // + r
      if (which == 2) {
        // Vt[b][a=n][s], r-consecutive in s -> pack 4 into one 8B store
        const int b = mbase >> 11, s = mbase & (S - 1);
        short4 p;
        p.x = f2bf(acc[mt][nt][0]); p.y = f2bf(acc[mt][nt][1]);
        p.z = f2bf(acc[mt][nt][2]); p.w = f2bf(acc[mt][nt][3]);
        *(short4*)&Vt[((size_t)b * A + n) * S + s] = p;
      } else {
        short* Outp = (which == 0) ? Qbf : Kbf;
        const float sc = (which == 0) ? qscale : 1.0f;
#pragma unroll
        for (int r = 0; r < 4; ++r)
          Outp[(size_t)(mbase + r) * A + n] = f2bf(acc[mt][nt][r] * sc);
      }
    }
  }
}

// ---------------------------------------------------------------------------
// Flash-causal attention with MFMA. One block = 256 threads = 4 waves;
// BM=64 query rows per block (16 per wave), BN=128 key tiles.
// Q pre-scaled bf16; scores accumulate fp32 in MFMA; P round-trips LDS
// (C-layout -> A-operand layout); online softmax per row via shfl_xor.
// LDS rows padded to 132 shorts to break 16-way bank conflicts.
// ---------------------------------------------------------------------------
#define LP 132
__global__ __launch_bounds__(256) void attn_mfma(
    const short* __restrict__ Qbf,
    const short* __restrict__ Kbf,
    const short* __restrict__ Vt,
    float* __restrict__ Out) {
  __shared__ short Ks[128 * LP];       // [key][a]
  __shared__ short Vs[128 * LP];       // [a][key]
  __shared__ short Ps[4][16 * LP];     // per-wave [row][key]

  const int tile = gridDim.x - 1 - blockIdx.x;   // heavy-first
  const int m0 = tile * 64;
  const int b = m0 >> 11;          // /S
  const int q0 = m0 & (S - 1);     // %S

  const int tid = threadIdx.x;
  const int wave = tid >> 6;
  const int lane = tid & 63;
  const int l16 = lane & 15;
  const int quad = lane >> 4;

  // Q A-fragments (row m = l16 within wave's 16 rows)
  short8 qfr[4];
  {
    const size_t qrow = (size_t)(b * S + q0 + wave * 16 + l16);
#pragma unroll
    for (int ks = 0; ks < 4; ++ks)
      qfr[ks] = *(const short8*)&Qbf[qrow * A + ks * 32 + quad * 8];
  }

  float m_run[4] = {-INFINITY, -INFINITY, -INFINITY, -INFINITY};
  float l_run[4] = {0.f, 0.f, 0.f, 0.f};
  floatx4 oacc[8] = {};

  const int myrow = q0 + wave * 16 + quad * 4;   // + r gives this lane's C-rows
  const int ntiles = (q0 + 64 + 127) >> 7;

  for (int t = 0; t < ntiles; ++t) {
    const int j0 = t * 128;
    // ---- stage K-tile [128 keys][128 a] ----
#pragma unroll
    for (int i = 0; i < 8; ++i) {
      const int f = tid + i * 256;
      const int row = f >> 4, c8 = f & 15;
      *(short8*)&Ks[row * LP + c8 * 8] =
          *(const short8*)&Kbf[(size_t)(b * S + j0 + row) * A + c8 * 8];
    }
    // ---- stage V-tile [128 a][128 keys] ----
#pragma unroll
    for (int i = 0; i < 8; ++i) {
      const int f = tid + i * 256;
      const int ar = f >> 4, c8 = f & 15;
      *(short8*)&Vs[ar * LP + c8 * 8] =
          *(const short8*)&Vt[((size_t)b * A + ar) * S + j0 + c8 * 8];
    }
    __syncthreads();

    // ---- S = Q.K^T  (8 n-tiles of 16 keys) ----
    floatx4 sc[8];
#pragma unroll
    for (int nt = 0; nt < 8; ++nt) {
      floatx4 c = {};
#pragma unroll
      for (int ks = 0; ks < 4; ++ks) {
        const short8 bfr = *(const short8*)&Ks[(nt * 16 + l16) * LP + ks * 32 + quad * 8];
        c = __builtin_amdgcn_mfma_f32_16x16x32_bf16(qfr[ks], bfr, c, 0, 0, 0);
      }
      sc[nt] = c;
    }

    // ---- causal mask + online softmax row stats ----
    float alpha[4];
#pragma unroll
    for (int r = 0; r < 4; ++r) {
      const int qr = myrow + r;
      float mx = -INFINITY;
#pragma unroll
      for (int nt = 0; nt < 8; ++nt) {
        const int key = j0 + nt * 16 + l16;
        if (key > qr) sc[nt][r] = -INFINITY;
        mx = fmaxf(mx, sc[nt][r]);
      }
      mx = fmaxf(mx, __shfl_xor(mx, 1));
      mx = fmaxf(mx, __shfl_xor(mx, 2));
      mx = fmaxf(mx, __shfl_xor(mx, 4));
      mx = fmaxf(mx, __shfl_xor(mx, 8));
      const float newm = fmaxf(m_run[r], mx);
      alpha[r] = __expf(m_run[r] - newm);   // -inf - finite -> 0 on first tile
      m_run[r] = newm;
      float s = 0.f;
#pragma unroll
      for (int nt = 0; nt < 8; ++nt) {
        const float p = __expf(sc[nt][r] - newm);   // masked: exp(-inf)=0
        sc[nt][r] = p;
        s += p;
      }
      s += __shfl_xor(s, 1);
      s += __shfl_xor(s, 2);
      s += __shfl_xor(s, 4);
      s += __shfl_xor(s, 8);
      l_run[r] = l_run[r] * alpha[r] + s;
    }

    // ---- rescale O, transpose P via LDS to A-operand layout ----
#pragma unroll
    for (int nt = 0; nt < 8; ++nt)
#pragma unroll
      for (int r = 0; r < 4; ++r)
        oacc[nt][r] *= alpha[r];

#pragma unroll
    for (int nt = 0; nt < 8; ++nt)
#pragma unroll
      for (int r = 0; r < 4; ++r)
        Ps[wave][(quad * 4 + r) * LP + nt * 16 + l16] = f2bf(sc[nt][r]);
    // wave-private buffer: in-wave LDS RAW ordering handled by compiler waits

    short8 pfr[4];
#pragma unroll
    for (int ks = 0; ks < 4; ++ks)
      pfr[ks] = *(const short8*)&Ps[wave][l16 * LP + ks * 32 + quad * 8];

    // ---- O += P.V  (8 output-dim tiles) ----
#pragma unroll
    for (int nt = 0; nt < 8; ++nt) {
#pragma unroll
      for (int ks = 0; ks < 4; ++ks) {
        const short8 vfr = *(const short8*)&Vs[(nt * 16 + l16) * LP + ks * 32 + quad * 8];
        oacc[nt] = __builtin_amdgcn_mfma_f32_16x16x32_bf16(pfr[ks], vfr, oacc[nt], 0, 0, 0);
      }
    }
    __syncthreads();   // protect Ks/Vs restage
  }

  // ---- epilogue: normalize and store fp32 ----
#pragma unroll
  for (int nt = 0; nt < 8; ++nt) {
#pragma unroll
    for (int r = 0; r < 4; ++r) {
      const size_t row = (size_t)(b * S + myrow + r);
      Out[row * A + nt * 16 + l16] = oacc[nt][r] / l_run[r];
    }
  }
}

extern "C" void kernel_launch(void* const* d_in, const int* in_sizes, int n_in,
                              void* d_out, int out_size, void* d_ws, size_t ws_size,
                              hipStream_t stream) {
  const float* X  = (const float*)d_in[0];  // embedded [B,S,E]
  const float* Wk = (const float*)d_in[1];  // [A,E]
  const float* Wq = (const float*)d_in[2];
  const float* Wv = (const float*)d_in[3];
  float* Out = (float*)d_out;               // [B,S,A]

  const size_t qkv_elems = (size_t)B * S * A;   // 1M elems, bf16 -> 2MB each
  short* Qbf = (short*)d_ws;
  short* Kbf = Qbf + qkv_elems;
  short* Vt  = Kbf + qkv_elems;

  dim3 pgrid(B * S / 128, 3);
  proj_gemm<<<pgrid, 256, 0, stream>>>(X, Wq, Wk, Wv, Qbf, Kbf, Vt);
  attn_mfma<<<B * S / 64, 256, 0, stream>>>(Qbf, Kbf, Vt, Out);
}